// Round 4
// baseline (176.598 us; speedup 1.0000x reference)
//
#include <hip/hip_runtime.h>
#include <stdint.h>

using f16 = _Float16;

typedef _Float16 f16x8 __attribute__((ext_vector_type(8)));
typedef _Float16 f16x4 __attribute__((ext_vector_type(4)));
typedef float f32x4 __attribute__((ext_vector_type(4)));

#define LOG2E 1.44269504088896340736f

__device__ __forceinline__ f16 f2h(float f) { return (f16)f; }  // RNE

#if __has_builtin(__builtin_amdgcn_exp2f)
__device__ __forceinline__ float fexp2(float x) { return __builtin_amdgcn_exp2f(x); }
#else
__device__ __forceinline__ float fexp2(float x) { return exp2f(x); }
#endif

typedef __attribute__((address_space(1))) const uint32_t gu32;
typedef __attribute__((address_space(3))) uint32_t lu32;

__device__ __forceinline__ void dma16(const void* g, void* l) {
  // global->LDS DMA, 16 B/lane. Global source is PER-LANE (caller includes
  // lane*16B); LDS dest is wave-uniform base + lane*16 auto-stride.
  __builtin_amdgcn_global_load_lds((gu32*)g, (lu32*)l, 16, 0, 0);
}

__device__ __forceinline__ f16x8 cvt8(const float* p) {
  const float4 a = *(const float4*)p;
  const float4 b = *(const float4*)(p + 4);
  f16x8 r;
  r[0] = (f16)a.x; r[1] = (f16)a.y; r[2] = (f16)a.z; r[3] = (f16)a.w;
  r[4] = (f16)b.x; r[5] = (f16)b.y; r[6] = (f16)b.z; r[7] = (f16)b.w;
  return r;
}

// B=4, C=64, N=4096.  Global in/out FP32; internal tensor-core path FP16.
// ws layout (bytes):
//   0     qa  f16 [4][4096][64]      (2 MB)  q*log2e, position-major
//   2 MB  ka2 f16 [4][8][4096][8]    (2 MB)  K: [b][c8][key'][8c], key' = key
//                                            with low-3 bits XORed by
//                                            ((key>>3&1)<<2)|(key>>4&1)  (bank fix)
//   4 MB  va3 f16 [4][512][64][8]    (2 MB)  V key-chunked: [b][k8][c][8k]
//   6 MB  y0  f32 [4][64][4096]      (4 MB)  gamma*attn_out, pre-BN
//   10 MB stats: gs1[64] | gs2[64]   (zeroed by pre block 0)

// ---------------------------------------------------------------------------
// pre: conv1d q/k over channels, v = vw@x+vb via MFMA.
// ---------------------------------------------------------------------------
__global__ __launch_bounds__(256, 2) void pam_pre(
    const float* __restrict__ x, const float* __restrict__ qw,
    const float* __restrict__ kw, const float* __restrict__ vw,
    const float* __restrict__ vb,
    f16* __restrict__ qa, f16* __restrict__ ka2, f16* __restrict__ va3,
    float* __restrict__ gz)
{
  __shared__ alignas(16) f16 xt[16 * 72];   // xt[n][c] f16, row stride 72
  const int tid = threadIdx.x;
  const int b = blockIdx.x >> 8;
  const int n0 = (blockIdx.x & 255) << 4;
  const int lane = tid & 63;
  const int wv = tid >> 6;
  const int quad = lane >> 4, l15 = lane & 15;

  if (blockIdx.x == 0 && tid < 128) gz[tid] = 0.f;   // gs1|gs2 zero-init

  // stage x[b][c][n0:+16] (fp32) transposed into xt[n][c] (f16)
  {
    const int c = tid >> 2;
    const int j0 = (tid & 3) << 2;
    const float4 v0 = *(const float4*)(x + ((size_t)(b * 64 + c) << 12) + n0 + j0);
    xt[(j0 + 0) * 72 + c] = f2h(v0.x);
    xt[(j0 + 1) * 72 + c] = f2h(v0.y);
    xt[(j0 + 2) * 72 + c] = f2h(v0.z);
    xt[(j0 + 3) * 72 + c] = f2h(v0.w);
  }
  __syncthreads();

  // conv over channel axis (SAME, zero pad)
  const float qw0 = qw[0], qw1 = qw[1], qw2 = qw[2];
  const float kw0 = kw[0], kw1 = kw[1], kw2 = kw[2];
  for (int p = 0; p < 4; ++p) {
    const int c = lane;
    const int jr = (p << 2) + wv;
    const int n = n0 + jr;
    const float xm = (c > 0) ? (float)xt[jr * 72 + c - 1] : 0.f;
    const float x0 = (float)xt[jr * 72 + c];
    const float xp = (c < 63) ? (float)xt[jr * 72 + c + 1] : 0.f;
    const float qv = (qw0 * xm + qw1 * x0 + qw2 * xp) * LOG2E;  // log2-domain
    const float kv = kw0 * xm + kw1 * x0 + kw2 * xp;
    qa[((size_t)((b << 12) + n) << 6) + c] = f2h(qv);
    // bank-conflict-fix storage permutation: flip key bits [2],[0] by bits [3],[4]
    const int np = n ^ ((((n >> 3) & 1) << 2) | ((n >> 4) & 1));
    ka2[((size_t)(b * 8 + (c >> 3)) << 15) + (np << 3) + (c & 7)] = f2h(kv);
  }

  // v[c][n] = vw @ x + vb via mfma (wave wv -> c rows [16wv,+16))
  {
    const f16x8 a0 = cvt8(vw + (wv * 16 + l15) * 64 + quad * 8);
    const f16x8 a1 = cvt8(vw + (wv * 16 + l15) * 64 + quad * 8 + 32);
    const f16x8 b0 = *(const f16x8*)&xt[l15 * 72 + quad * 8];
    const f16x8 b1 = *(const f16x8*)&xt[l15 * 72 + quad * 8 + 32];
    f32x4 z = {0.f, 0.f, 0.f, 0.f};
    z = __builtin_amdgcn_mfma_f32_16x16x32_f16(a0, b0, z, 0, 0, 0);
    z = __builtin_amdgcn_mfma_f32_16x16x32_f16(a1, b1, z, 0, 0, 0);
    const int cobase = wv * 16 + quad * 4;
    for (int r = 0; r < 4; ++r) {
      const int co = cobase + r;
      const int n = n0 + l15;
      const float val = z[r] + vb[co];
      // va3[b][n>>3][co][n&7]
      va3[(((size_t)(b * 512 + (n >> 3))) << 9) + (co << 3) + (n & 7)] = f2h(val);
    }
  }
}

// ---------------------------------------------------------------------------
// attention v19b = v18 dataflow, doubled blocking (v19 with the addrspacecast
// compile fix: no local pointer-arrays into dynamic LDS; base + offset only):
//  - 1024 threads, 16 waves = (qh 0..1) x (ks 0..7); 64 queries/block,
//    256-key double-buffered tiles, 16 iters.  Grid 256 = 1 block/CU.
//    Total L2->LDS staging traffic halves (512 -> 256 MB); barrier-drain
//    events halve (32 -> 16) with 2x compute per iter to hide each drain.
//  - dynamic LDS 128 KB (2 x (32K K-tile + 32K V-tile)); merge buffer ldsO
//    reuses the staging region after the main loop.
//  - bank-fix: ka2 stores keys at XOR-permuted positions (see pam_pre);
//    the gather XORs the same mask -> each 16-lane read phase spreads
//    over all 8 bank quads (2-way, free) instead of 4-way on banks 0-15.
//  - per-wave dataflow unchanged from v18: K-perm gather makes S^T regs
//    land in PV B-frag k-order (zero-shuffle P); O^T PV via 16x16x32;
//    lane-local online softmax + defer-max (THR=8, log2 domain).
// ---------------------------------------------------------------------------
__global__ __launch_bounds__(1024, 4) void pam_attn(
    const f16* __restrict__ qa, const f16* __restrict__ ka2,
    const f16* __restrict__ va3, const float* __restrict__ gam,
    float* __restrict__ y0, float* __restrict__ gs1, float* __restrict__ gs2)
{
  extern __shared__ char smem[];
  // [0,64K): kbuf[2][16384] f16  [c8 8][key 256][8c] per buffer
  // [64K,128K): vbuf[2][16384] f16  [k8 32][c 64][8k] per buffer
  f16* const kbase = (f16*)smem;
  f16* const vbase2 = (f16*)(smem + 65536);
  float* const ldsO = (float*)smem;              // [64 q][65 c], reuse after loop
  __shared__ float ldsM[8][64], ldsL[8][64], ldsMg[64], ldsInv[64];

  const int tid = threadIdx.x;
  const int wv = tid >> 6, lane = tid & 63;
  const int quad = lane >> 4, l15 = lane & 15;
  const int ks = wv & 7, qh = wv >> 3;
  const int slot = (int)blockIdx.x & 7;
  const int b = slot >> 1;                       // 2 XCDs per batch
  const int qb = (((int)blockIdx.x >> 3) << 1) | (slot & 1);   // 0..63
  const int qb0 = qb << 6;
  const int phase = qb & 15;                     // anti-convoy rotation

  const int bn = b << 12;
  // Q fragments, 2 q-tiles (B-operand: col=l15=q, k=quad*8+j over channels)
  f16x8 bq00, bq01, bq10, bq11;
  {
    const f16* qp0 = qa + ((size_t)(bn + qb0 + qh * 32 + l15) << 6) + quad * 8;
    bq00 = *(const f16x8*)qp0;
    bq01 = *(const f16x8*)(qp0 + 32);
    const f16* qp1 = qp0 + (16 << 6);
    bq10 = *(const f16x8*)qp1;
    bq11 = *(const f16x8*)(qp1 + 32);
  }

  // staging bases (PER-LANE source: + lane*8 f16 = 16 B/lane).
  // K: wave wv stages c8-group wv>>1, key-half wv&1 (128 keys x 8c = 2 KB).
  // V: wave wv stages k8-chunks {2wv, 2wv+1} (2 x 1 KB per tile).
  const f16* kg0 = ka2 + (((size_t)(b * 8 + (wv >> 1))) << 15)
                 + ((wv & 1) << 10) + (lane << 3);
  const f16* vg0 = va3 + ((size_t)b << 18) + (wv << 10) + (lane << 3);

  f32x4 o0[4] = {}, o1[4] = {};   // O^T: col=l15=q, row c = ct*16+quad*4+r
  float m0 = -1e30f, lp0 = 0.f, m1 = -1e30f, lp1 = 0.f;

  // stage tile 'phase' into buf 0
  dma16(kg0 + ((size_t)phase << 11),       kbase + (wv << 10));
  dma16(kg0 + ((size_t)phase << 11) + 512, kbase + (wv << 10) + 512);
  dma16(vg0 + ((size_t)phase << 14),       vbase2 + (wv << 10));
  dma16(vg0 + ((size_t)phase << 14) + 512, vbase2 + (wv << 10) + 512);
  __syncthreads();

  // K gather: lane l15 reads stored position pos_t ^ xm; storage holds key n
  // at position n ^ mask(n[4:3]), so content = actual key pos_t, i.e. S^T reg
  // r of quad holds key ks*32 + quad*8 + t*4 + r == PV k-order.
  const int u = l15 >> 2;
  const int xm = ((u & 1) << 2) | (u >> 1);
  const int pos0 = (ks << 5) + (u << 3) + (l15 & 3);
  const int koff0 = (pos0 ^ xm) << 3;
  const int koff1 = koff0 ^ 32;                 // pos0|4, same XOR
  const int vbase = ((ks * 4 + quad) << 9) + (l15 << 3);

#pragma unroll 1
  for (int kt = 0; kt < 16; ++kt) {
    const int cur = kt & 1;
    if (kt < 15) {
      const int tn = (kt + 1 + phase) & 15;
      f16* kd = kbase + ((cur ^ 1) << 14) + (wv << 10);
      f16* vd = vbase2 + ((cur ^ 1) << 14) + (wv << 10);
      dma16(kg0 + ((size_t)tn << 11),       kd);
      dma16(kg0 + ((size_t)tn << 11) + 512, kd + 512);
      dma16(vg0 + ((size_t)tn << 14),       vd);
      dma16(vg0 + ((size_t)tn << 14) + 512, vd + 512);
    }

    const f16* kc = kbase + (cur << 14);
    const f16* vc = vbase2 + (cur << 14);
    const f16x8 ak00 = *(const f16x8*)(kc + (quad << 11) + koff0);
    const f16x8 ak01 = *(const f16x8*)(kc + ((4 + quad) << 11) + koff0);
    const f16x8 ak10 = *(const f16x8*)(kc + (quad << 11) + koff1);
    const f16x8 ak11 = *(const f16x8*)(kc + ((4 + quad) << 11) + koff1);

    // S^T[32 key (permuted)][16 q] x 2 q-tiles, contraction over 64 channels
    f32x4 za0, zb0, za1, zb1;
    {
      f32x4 z = {0.f, 0.f, 0.f, 0.f};
      z = __builtin_amdgcn_mfma_f32_16x16x32_f16(ak00, bq00, z, 0, 0, 0);
      za0 = __builtin_amdgcn_mfma_f32_16x16x32_f16(ak01, bq01, z, 0, 0, 0);
    }
    {
      f32x4 z = {0.f, 0.f, 0.f, 0.f};
      z = __builtin_amdgcn_mfma_f32_16x16x32_f16(ak10, bq00, z, 0, 0, 0);
      zb0 = __builtin_amdgcn_mfma_f32_16x16x32_f16(ak11, bq01, z, 0, 0, 0);
    }
    {
      f32x4 z = {0.f, 0.f, 0.f, 0.f};
      z = __builtin_amdgcn_mfma_f32_16x16x32_f16(ak00, bq10, z, 0, 0, 0);
      za1 = __builtin_amdgcn_mfma_f32_16x16x32_f16(ak01, bq11, z, 0, 0, 0);
    }
    {
      f32x4 z = {0.f, 0.f, 0.f, 0.f};
      z = __builtin_amdgcn_mfma_f32_16x16x32_f16(ak10, bq10, z, 0, 0, 0);
      zb1 = __builtin_amdgcn_mfma_f32_16x16x32_f16(ak11, bq11, z, 0, 0, 0);
    }

    // ---- softmax + P pack, q-tile 0 ----
    f16x8 pa0, pa1;
    {
      float tmax = fmaxf(fmaxf(fmaxf(za0[0], za0[1]), fmaxf(za0[2], za0[3])),
                         fmaxf(fmaxf(zb0[0], zb0[1]), fmaxf(zb0[2], zb0[3])));
      tmax = fmaxf(tmax, __shfl_xor(tmax, 16, 64));
      tmax = fmaxf(tmax, __shfl_xor(tmax, 32, 64));
      const bool need = !__all(tmax <= m0 + 8.f);
      const float mn = need ? fmaxf(m0, tmax) : m0;
      const float p0 = fexp2(za0[0] - mn), p1 = fexp2(za0[1] - mn);
      const float p2 = fexp2(za0[2] - mn), p3 = fexp2(za0[3] - mn);
      const float p4 = fexp2(zb0[0] - mn), p5 = fexp2(zb0[1] - mn);
      const float p6 = fexp2(zb0[2] - mn), p7 = fexp2(zb0[3] - mn);
      const float ts = ((p0 + p1) + (p2 + p3)) + ((p4 + p5) + (p6 + p7));
      pa0[0] = f2h(p0); pa0[1] = f2h(p1); pa0[2] = f2h(p2); pa0[3] = f2h(p3);
      pa0[4] = f2h(p4); pa0[5] = f2h(p5); pa0[6] = f2h(p6); pa0[7] = f2h(p7);
      if (need) {
        const float al = fexp2(m0 - mn);
        lp0 = lp0 * al + ts;
        m0 = mn;
#pragma unroll
        for (int ct = 0; ct < 4; ++ct)
          for (int r = 0; r < 4; ++r) o0[ct][r] *= al;
      } else {
        lp0 += ts;
      }
    }
    // ---- softmax + P pack, q-tile 1 ----
    {
      float tmax = fmaxf(fmaxf(fmaxf(za1[0], za1[1]), fmaxf(za1[2], za1[3])),
                         fmaxf(fmaxf(zb1[0], zb1[1]), fmaxf(zb1[2], zb1[3])));
      tmax = fmaxf(tmax, __shfl_xor(tmax, 16, 64));
      tmax = fmaxf(tmax, __shfl_xor(tmax, 32, 64));
      const bool need = !__all(tmax <= m1 + 8.f);
      const float mn = need ? fmaxf(m1, tmax) : m1;
      const float p0 = fexp2(za1[0] - mn), p1 = fexp2(za1[1] - mn);
      const float p2 = fexp2(za1[2] - mn), p3 = fexp2(za1[3] - mn);
      const float p4 = fexp2(zb1[0] - mn), p5 = fexp2(zb1[1] - mn);
      const float p6 = fexp2(zb1[2] - mn), p7 = fexp2(zb1[3] - mn);
      const float ts = ((p0 + p1) + (p2 + p3)) + ((p4 + p5) + (p6 + p7));
      pa1[0] = f2h(p0); pa1[1] = f2h(p1); pa1[2] = f2h(p2); pa1[3] = f2h(p3);
      pa1[4] = f2h(p4); pa1[5] = f2h(p5); pa1[6] = f2h(p6); pa1[7] = f2h(p7);
      if (need) {
        const float al = fexp2(m1 - mn);
        lp1 = lp1 * al + ts;
        m1 = mn;
#pragma unroll
        for (int ct = 0; ct < 4; ++ct)
          for (int r = 0; r < 4; ++r) o1[ct][r] *= al;
      } else {
        lp1 += ts;
      }
    }

    // O^T += V * P^T : one K=32 MFMA per (16-channel tile, q-tile)
#pragma unroll
    for (int ct = 0; ct < 4; ++ct) {
      const f16x8 av = *(const f16x8*)(vc + vbase + ct * 128);
      o0[ct] = __builtin_amdgcn_mfma_f32_16x16x32_f16(av, pa0, o0[ct], 0, 0, 0);
      o1[ct] = __builtin_amdgcn_mfma_f32_16x16x32_f16(av, pa1, o1[ct], 0, 0, 0);
    }
    __syncthreads();   // DMA landed + all waves done with buffers
  }

  // publish per-wave online state (m quad-uniform; lp reduced across quads)
  lp0 += __shfl_xor(lp0, 16, 64);
  lp0 += __shfl_xor(lp0, 32, 64);
  lp1 += __shfl_xor(lp1, 16, 64);
  lp1 += __shfl_xor(lp1, 32, 64);
  if (quad == 0) {
    ldsM[ks][qh * 32 + l15] = m0;
    ldsL[ks][qh * 32 + l15] = lp0;
    ldsM[ks][qh * 32 + 16 + l15] = m1;
    ldsL[ks][qh * 32 + 16 + l15] = lp1;
  }
  __syncthreads();

  // zero merge buffer (staging region is dead now) + per-query global stats
  for (int i = tid; i < 64 * 65; i += 1024) ldsO[i] = 0.f;
  if (tid < 64) {
    float M = ldsM[0][tid];
#pragma unroll
    for (int k = 1; k < 8; ++k) M = fmaxf(M, ldsM[k][tid]);
    float lt = 0.f;
#pragma unroll
    for (int k = 0; k < 8; ++k) lt += ldsL[k][tid] * fexp2(ldsM[k][tid] - M);
    ldsMg[tid] = M;
    ldsInv[tid] = 1.f / lt;
  }
  __syncthreads();

  // m-aware merge of partial O^T across the 8 key-split waves (sc lane-local)
  {
    const int q0i = qh * 32 + l15, q1i = q0i + 16;
    const float sc0 = fexp2(m0 - ldsMg[q0i]);
    const float sc1 = fexp2(m1 - ldsMg[q1i]);
#pragma unroll
    for (int ct = 0; ct < 4; ++ct)
      for (int r = 0; r < 4; ++r) {
        const int c = ct * 16 + quad * 4 + r;
        atomicAdd(&ldsO[q0i * 65 + c], o0[ct][r] * sc0);
        atomicAdd(&ldsO[q1i * 65 + c], o1[ct][r] * sc1);
      }
  }
  __syncthreads();

  // epilogue: y0[b][c][n] = gamma * O / l ; BN partial sums
  const float g = gam[0];
  {
    const int c = tid >> 4;              // 0..63
    const int q0 = (tid & 15) << 2;      // 0..60
    float4 v4;
    float* vp = &v4.x;
    float s1 = 0.f, s2 = 0.f;
#pragma unroll
    for (int r = 0; r < 4; ++r) {
      const float val = g * ldsO[(q0 + r) * 65 + c] * ldsInv[q0 + r];
      vp[r] = val; s1 += val; s2 += val * val;
    }
    *(float4*)(y0 + ((size_t)(b * 64 + c) << 12) + qb0 + q0) = v4;
    s1 += __shfl_xor(s1, 1, 64);
    s2 += __shfl_xor(s2, 1, 64);
    s1 += __shfl_xor(s1, 2, 64);
    s2 += __shfl_xor(s2, 2, 64);
    s1 += __shfl_xor(s1, 4, 64);
    s2 += __shfl_xor(s2, 4, 64);
    s1 += __shfl_xor(s1, 8, 64);
    s2 += __shfl_xor(s2, 8, 64);
    if ((tid & 15) == 0) {
      atomicAdd(&gs1[c], s1);
      atomicAdd(&gs2[c], s2);
    }
  }
}

// ---------------------------------------------------------------------------
// apply: BN(scale/shift from gs1/gs2) + residual.
// ---------------------------------------------------------------------------
__global__ __launch_bounds__(256, 2) void pam_apply(
    const float* __restrict__ y0, const float* __restrict__ x,
    const float* __restrict__ gs1, const float* __restrict__ gs2,
    const float* __restrict__ bnw, const float* __restrict__ bnb,
    float* __restrict__ out)
{
  const int i = (blockIdx.x * 256 + threadIdx.x) << 2;   // 4 elems/thread
  const int c = (i >> 12) & 63;
  const float inv_n = 1.f / 16384.f;
  const float mean = gs1[c] * inv_n;
  const float var = fmaxf(gs2[c] * inv_n - mean * mean, 0.f);
  const float sc = bnw[c] * rsqrtf(var + 1e-5f);
  const float sh = bnb[c] - mean * sc;
  const float4 y = *(const float4*)(y0 + i);
  const float4 xv = *(const float4*)(x + i);
  float4 r;
  r.x = y.x * sc + sh + xv.x;
  r.y = y.y * sc + sh + xv.y;
  r.z = y.z * sc + sh + xv.z;
  r.w = y.w * sc + sh + xv.w;
  *(float4*)(out + i) = r;
}

// ---------------------------------------------------------------------------
extern "C" void kernel_launch(void* const* d_in, const int* in_sizes, int n_in,
                              void* d_out, int out_size, void* d_ws, size_t ws_size,
                              hipStream_t stream)
{
  (void)in_sizes; (void)n_in; (void)out_size; (void)ws_size;
  const float* x   = (const float*)d_in[0];
  const float* qw  = (const float*)d_in[1];
  const float* kw  = (const float*)d_in[2];
  const float* vw  = (const float*)d_in[3];
  const float* vb  = (const float*)d_in[4];
  const float* gam = (const float*)d_in[5];
  const float* bnw = (const float*)d_in[6];
  const float* bnb = (const float*)d_in[7];

  char* ws = (char*)d_ws;
  f16*   qa  = (f16*)(ws);
  f16*   ka2 = (f16*)(ws + (2u << 20));
  f16*   va3 = (f16*)(ws + (4u << 20));
  float* y0  = (float*)(ws + (6u << 20));
  float* gs1 = (float*)(ws + (10u << 20));          // 64 floats
  float* gs2 = (float*)(ws + (10u << 20) + 256);    // 64 floats (contiguous)

  // one-time opt-in for 128 KB dynamic LDS on pam_attn (host-side config;
  // not a stream op, graph-capture safe)
  static bool lds_init = false;
  if (!lds_init) {
    (void)hipFuncSetAttribute((const void*)pam_attn,
                              hipFuncAttributeMaxDynamicSharedMemorySize, 131072);
    lds_init = true;
  }

  pam_pre  <<<1024, 256, 0, stream>>>(x, qw, kw, vw, vb, qa, ka2, va3, gs1);
  pam_attn <<<256, 1024, 131072, stream>>>(qa, ka2, va3, gam, y0, gs1, gs2);
  pam_apply<<<1024, 256, 0, stream>>>(y0, x, gs1, gs2, bnw, bnb, (float*)d_out);
}

// Round 5
// 161.057 us; speedup vs baseline: 1.0965x; 1.0965x over previous
//
#include <hip/hip_runtime.h>
#include <stdint.h>

using f16 = _Float16;

typedef _Float16 f16x8 __attribute__((ext_vector_type(8)));
typedef _Float16 f16x4 __attribute__((ext_vector_type(4)));
typedef float f32x4 __attribute__((ext_vector_type(4)));

#define LOG2E 1.44269504088896340736f

__device__ __forceinline__ f16 f2h(float f) { return (f16)f; }  // RNE

#if __has_builtin(__builtin_amdgcn_exp2f)
__device__ __forceinline__ float fexp2(float x) { return __builtin_amdgcn_exp2f(x); }
#else
__device__ __forceinline__ float fexp2(float x) { return exp2f(x); }
#endif

typedef __attribute__((address_space(1))) const uint32_t gu32;
typedef __attribute__((address_space(3))) uint32_t lu32;

__device__ __forceinline__ void dma16(const void* g, void* l) {
  // global->LDS DMA, 16 B/lane. Global source is PER-LANE (caller includes
  // lane*16B); LDS dest is wave-uniform base + lane*16 auto-stride.
  __builtin_amdgcn_global_load_lds((gu32*)g, (lu32*)l, 16, 0, 0);
}

__device__ __forceinline__ f16x8 cvt8(const float* p) {
  const float4 a = *(const float4*)p;
  const float4 b = *(const float4*)(p + 4);
  f16x8 r;
  r[0] = (f16)a.x; r[1] = (f16)a.y; r[2] = (f16)a.z; r[3] = (f16)a.w;
  r[4] = (f16)b.x; r[5] = (f16)b.y; r[6] = (f16)b.z; r[7] = (f16)b.w;
  return r;
}

// B=4, C=64, N=4096.  Global in/out FP32; internal tensor-core path FP16.
// ws layout (bytes):
//   0     qa  f16 [4][4096][64]      (2 MB)  q*log2e, position-major
//   2 MB  ka2 f16 [4][8][4096][8]    (2 MB)  K channel-chunked: [b][c8][key][8c]
//   4 MB  va3 f16 [4][512][64][8]    (2 MB)  V key-chunked:     [b][k8][c][8k]
//   6 MB  y0  f32 [4][64][4096]      (4 MB)  gamma*attn_out, pre-BN
//   10 MB stats: gs1[64] | gs2[64]   (zeroed by pre block 0)

// ---------------------------------------------------------------------------
// pre: conv1d q/k over channels, v = vw@x+vb via MFMA.  (K storage is plain
// again: the v20 attention needs no key permutation.)
// ---------------------------------------------------------------------------
__global__ __launch_bounds__(256, 2) void pam_pre(
    const float* __restrict__ x, const float* __restrict__ qw,
    const float* __restrict__ kw, const float* __restrict__ vw,
    const float* __restrict__ vb,
    f16* __restrict__ qa, f16* __restrict__ ka2, f16* __restrict__ va3,
    float* __restrict__ gz)
{
  __shared__ alignas(16) f16 xt[16 * 72];   // xt[n][c] f16, row stride 72
  const int tid = threadIdx.x;
  const int b = blockIdx.x >> 8;
  const int n0 = (blockIdx.x & 255) << 4;
  const int lane = tid & 63;
  const int wv = tid >> 6;
  const int quad = lane >> 4, l15 = lane & 15;

  if (blockIdx.x == 0 && tid < 128) gz[tid] = 0.f;   // gs1|gs2 zero-init

  // stage x[b][c][n0:+16] (fp32) transposed into xt[n][c] (f16)
  {
    const int c = tid >> 2;
    const int j0 = (tid & 3) << 2;
    const float4 v0 = *(const float4*)(x + ((size_t)(b * 64 + c) << 12) + n0 + j0);
    xt[(j0 + 0) * 72 + c] = f2h(v0.x);
    xt[(j0 + 1) * 72 + c] = f2h(v0.y);
    xt[(j0 + 2) * 72 + c] = f2h(v0.z);
    xt[(j0 + 3) * 72 + c] = f2h(v0.w);
  }
  __syncthreads();

  // conv over channel axis (SAME, zero pad)
  const float qw0 = qw[0], qw1 = qw[1], qw2 = qw[2];
  const float kw0 = kw[0], kw1 = kw[1], kw2 = kw[2];
  for (int p = 0; p < 4; ++p) {
    const int c = lane;
    const int jr = (p << 2) + wv;
    const int n = n0 + jr;
    const float xm = (c > 0) ? (float)xt[jr * 72 + c - 1] : 0.f;
    const float x0 = (float)xt[jr * 72 + c];
    const float xp = (c < 63) ? (float)xt[jr * 72 + c + 1] : 0.f;
    const float qv = (qw0 * xm + qw1 * x0 + qw2 * xp) * LOG2E;  // log2-domain
    const float kv = kw0 * xm + kw1 * x0 + kw2 * xp;
    qa[((size_t)((b << 12) + n) << 6) + c] = f2h(qv);
    ka2[((size_t)(b * 8 + (c >> 3)) << 15) + (n << 3) + (c & 7)] = f2h(kv);
  }

  // v[c][n] = vw @ x + vb via mfma (wave wv -> c rows [16wv,+16))
  {
    const f16x8 a0 = cvt8(vw + (wv * 16 + l15) * 64 + quad * 8);
    const f16x8 a1 = cvt8(vw + (wv * 16 + l15) * 64 + quad * 8 + 32);
    const f16x8 b0 = *(const f16x8*)&xt[l15 * 72 + quad * 8];
    const f16x8 b1 = *(const f16x8*)&xt[l15 * 72 + quad * 8 + 32];
    f32x4 z = {0.f, 0.f, 0.f, 0.f};
    z = __builtin_amdgcn_mfma_f32_16x16x32_f16(a0, b0, z, 0, 0, 0);
    z = __builtin_amdgcn_mfma_f32_16x16x32_f16(a1, b1, z, 0, 0, 0);
    const int cobase = wv * 16 + quad * 4;
    for (int r = 0; r < 4; ++r) {
      const int co = cobase + r;
      const int n = n0 + l15;
      const float val = z[r] + vb[co];
      // va3[b][n>>3][co][n&7]
      va3[(((size_t)(b * 512 + (n >> 3))) << 9) + (co << 3) + (n & 7)] = f2h(val);
    }
  }
}

// ---------------------------------------------------------------------------
// attention v20 = v18 config (512 thr, 8 waves, 2 blocks/CU) with the sync
// structure replaced by a COUNTED-VMCNT pipeline (T3/T4):
//  - 64-key tiles, QUAD-buffered (4 x (8K K + 8K V) = 64 KB dynamic LDS),
//    prefetch distance 2.  Each wave issues 2 dma16/iter; end-of-iter sync is
//    `s_waitcnt vmcnt(2)` + raw s_barrier -- tile t+2's DMAs stay IN FLIGHT
//    across the barrier (~2 iterations to land).  __syncthreads' vmcnt(0)
//    drain -- which serialized every previous version -- is gone.
//  - 16 keys/wave/tile makes all layouts IDENTITY: 16x16 C-layout
//    (row=quad*4+r) == 16x16x16 A/B k-layout (k=quad*4+j).  No K permutation,
//    no XOR bank-fix, no P reshuffle; K reads are contiguous b128 (2-way,
//    free), V reads contiguous b64 (free).
//  - QK^T: 2x 16x16x32 chained over channel halves.  PV: 4x 16x16x16.
//  - lane-local online softmax + defer-max (THR=8, log2 domain) as v18.
// Waves = (qh 0..1 of 16q, ks 0..3 of 16 keys), 64 iters.  Grid 512.
// ---------------------------------------------------------------------------
__global__ __launch_bounds__(512, 2) void pam_attn(
    const f16* __restrict__ qa, const f16* __restrict__ ka2,
    const f16* __restrict__ va3, const float* __restrict__ gam,
    float* __restrict__ y0, float* __restrict__ gs1, float* __restrict__ gs2)
{
  extern __shared__ char smem[];
  // [0,32K):  kbuf[4][4096] f16  slot = [c8 8][key 64][8c]
  // [32K,64K): vbuf[4][4096] f16  slot = [k8 8][c 64][8k]
  f16* const kbase = (f16*)smem;
  f16* const vbase = (f16*)(smem + 32768);
  float* const ldsO = (float*)smem;          // [32 q][65 c], reuse after drain
  __shared__ float ldsM[4][32], ldsL[4][32], ldsMg[32], ldsInv[32];

  const int tid = threadIdx.x;
  const int wv = tid >> 6, lane = tid & 63;
  const int quad = lane >> 4, l15 = lane & 15;
  const int ks = wv & 3, qh = wv >> 2;
  const int b = blockIdx.x & 3;
  const int qb = blockIdx.x >> 2;          // 0..127
  const int qb0 = qb << 5;
  const int phase = qb & 63;               // anti-convoy rotation (64 tiles)

  const int bn = b << 12;
  // Q fragments (B-operand: col=l15=q, k=quad*8+j over channels)
  f16x8 bq0, bq1;
  {
    const int q = qb0 + qh * 16 + l15;
    const f16* qp = qa + ((size_t)(bn + q) << 6) + quad * 8;
    bq0 = *(const f16x8*)qp;
    bq1 = *(const f16x8*)(qp + 32);
  }

  // staging bases (PER-LANE source: + lane*8 f16 = 16 B/lane).
  // K: wave wv stages c8-plane wv (64 keys x 8c = 1 KB per tile).
  // V: wave wv stages k8-chunk wv (64 c x 8k = 1 KB per tile).
  const f16* kg0 = ka2 + (((size_t)(b * 8 + wv)) << 15) + (lane << 3);
  const f16* vg0 = va3 + ((size_t)b << 18) + (wv << 9) + (lane << 3);

  f32x4 o[4] = {};                 // O^T: col=l15=q, row c = ct*16+quad*4+r
  float m = -1e30f, lp = 0.f;

  // prologue: stage tiles 0,1 into slots 0,1; wait only for tile 0
  {
    const int g0 = phase;                  // (0 + phase) & 63
    const int g1 = (1 + phase) & 63;
    dma16(kg0 + ((size_t)g0 << 9),  kbase + (wv << 9));
    dma16(vg0 + ((size_t)g0 << 12), vbase + (wv << 9));
    dma16(kg0 + ((size_t)g1 << 9),  kbase + 4096 + (wv << 9));
    dma16(vg0 + ((size_t)g1 << 12), vbase + 4096 + (wv << 9));
  }
  asm volatile("s_waitcnt vmcnt(2)" ::: "memory");
  __builtin_amdgcn_s_barrier();

  const int krow = ((ks << 4) + l15) << 3;                       // key row f16
  const int vrow = ((ks * 2 + (quad >> 1)) << 9) + ((quad & 1) << 2);

#pragma unroll 1
  for (int kt = 0; kt < 64; ++kt) {
    const int slot = kt & 3;
    // prefetch tile kt+2 (distance 2; wraps harmlessly at the tail)
    {
      const int g = (kt + 2 + phase) & 63;
      const int ps = ((kt + 2) & 3) << 12;
      dma16(kg0 + ((size_t)g << 9),  kbase + ps + (wv << 9));
      dma16(vg0 + ((size_t)g << 12), vbase + ps + (wv << 9));
    }

    const f16* kc = kbase + (slot << 12);
    const f16* vc = vbase + (slot << 12);
    const f16x8 ak0 = *(const f16x8*)(kc + (quad << 9) + krow);        // c 0..31
    const f16x8 ak1 = *(const f16x8*)(kc + ((4 + quad) << 9) + krow);  // c 32..63

    // S^T[16 key][16 q], contraction over 64 channels
    f32x4 z;
    {
      f32x4 zz = {0.f, 0.f, 0.f, 0.f};
      zz = __builtin_amdgcn_mfma_f32_16x16x32_f16(ak0, bq0, zz, 0, 0, 0);
      z  = __builtin_amdgcn_mfma_f32_16x16x32_f16(ak1, bq1, zz, 0, 0, 0);
    }

    // online softmax: lane holds keys quad*4+{0..3} for query q=l15
    float tmax = fmaxf(fmaxf(z[0], z[1]), fmaxf(z[2], z[3]));
    tmax = fmaxf(tmax, __shfl_xor(tmax, 16, 64));
    tmax = fmaxf(tmax, __shfl_xor(tmax, 32, 64));
    const bool need = !__all(tmax <= m + 8.f);    // defer-max, THR=8
    const float mn = need ? fmaxf(m, tmax) : m;

    const float p0 = fexp2(z[0] - mn);
    const float p1 = fexp2(z[1] - mn);
    const float p2 = fexp2(z[2] - mn);
    const float p3 = fexp2(z[3] - mn);
    const float ts = (p0 + p1) + (p2 + p3);

    f16x4 pa;   // P B-frag: k = quad*4+j == S^T reg order (identity)
    pa[0] = f2h(p0); pa[1] = f2h(p1); pa[2] = f2h(p2); pa[3] = f2h(p3);

    if (need) {
      const float al = fexp2(m - mn);   // lane-local (q in column)
      lp = lp * al + ts;
      m = mn;
#pragma unroll
      for (int ct = 0; ct < 4; ++ct)
        for (int r = 0; r < 4; ++r) o[ct][r] *= al;
    } else {
      lp += ts;
    }

    // O^T += V * P^T : 16x16x16 per 16-channel tile (A = V[16c x 16k])
#pragma unroll
    for (int ct = 0; ct < 4; ++ct) {
      const f16x4 av = *(const f16x4*)(vc + vrow + ((ct * 16 + l15) << 3));
      o[ct] = __builtin_amdgcn_mfma_f32_16x16x16f16(av, pa, o[ct], 0, 0, 0);
    }

    // counted sync: drain tile kt+1's DMAs, leave kt+2's 2 in flight
    asm volatile("s_waitcnt vmcnt(2)" ::: "memory");
    __builtin_amdgcn_s_barrier();
  }

  // drain trailing prefetches before reusing the staging LDS as ldsO
  asm volatile("s_waitcnt vmcnt(0)" ::: "memory");

  // publish per-wave online state (m quad-uniform; lp reduced across quads)
  lp += __shfl_xor(lp, 16, 64);
  lp += __shfl_xor(lp, 32, 64);
  if (quad == 0) {
    ldsM[ks][qh * 16 + l15] = m;
    ldsL[ks][qh * 16 + l15] = lp;
  }
  __syncthreads();

  // zero merge buffer + per-query global max/denom (4 key-slices)
  for (int i = tid; i < 32 * 65; i += 512) ldsO[i] = 0.f;
  if (tid < 32) {
    const float M = fmaxf(fmaxf(ldsM[0][tid], ldsM[1][tid]),
                          fmaxf(ldsM[2][tid], ldsM[3][tid]));
    const float lt = ldsL[0][tid] * fexp2(ldsM[0][tid] - M) +
                     ldsL[1][tid] * fexp2(ldsM[1][tid] - M) +
                     ldsL[2][tid] * fexp2(ldsM[2][tid] - M) +
                     ldsL[3][tid] * fexp2(ldsM[3][tid] - M);
    ldsMg[tid] = M;
    ldsInv[tid] = 1.f / lt;
  }
  __syncthreads();

  // m-aware merge of partial O^T across the 4 key-split waves (sc lane-local)
  {
    const int q = qh * 16 + l15;
    const float sc = fexp2(m - ldsMg[q]);
#pragma unroll
    for (int ct = 0; ct < 4; ++ct)
      for (int r = 0; r < 4; ++r)
        atomicAdd(&ldsO[q * 65 + ct * 16 + quad * 4 + r], o[ct][r] * sc);
  }
  __syncthreads();

  // epilogue: y0[b][c][n] = gamma * O / l ; BN partial sums
  const float g = gam[0];
  {
    const int c = tid >> 3;              // 0..63
    const int q0 = (tid & 7) << 2;       // 0..28
    float4 v4;
    float* vp = &v4.x;
    float s1 = 0.f, s2 = 0.f;
    for (int r = 0; r < 4; ++r) {
      const float val = g * ldsO[(q0 + r) * 65 + c] * ldsInv[q0 + r];
      vp[r] = val; s1 += val; s2 += val * val;
    }
    *(float4*)(y0 + ((size_t)(b * 64 + c) << 12) + qb0 + q0) = v4;
    s1 += __shfl_xor(s1, 1, 64);
    s2 += __shfl_xor(s2, 1, 64);
    s1 += __shfl_xor(s1, 2, 64);
    s2 += __shfl_xor(s2, 2, 64);
    s1 += __shfl_xor(s1, 4, 64);
    s2 += __shfl_xor(s2, 4, 64);
    if ((tid & 7) == 0) {
      atomicAdd(&gs1[c], s1);
      atomicAdd(&gs2[c], s2);
    }
  }
}

// ---------------------------------------------------------------------------
// apply: BN(scale/shift from gs1/gs2) + residual.
// ---------------------------------------------------------------------------
__global__ __launch_bounds__(256, 2) void pam_apply(
    const float* __restrict__ y0, const float* __restrict__ x,
    const float* __restrict__ gs1, const float* __restrict__ gs2,
    const float* __restrict__ bnw, const float* __restrict__ bnb,
    float* __restrict__ out)
{
  const int i = (blockIdx.x * 256 + threadIdx.x) << 2;   // 4 elems/thread
  const int c = (i >> 12) & 63;
  const float inv_n = 1.f / 16384.f;
  const float mean = gs1[c] * inv_n;
  const float var = fmaxf(gs2[c] * inv_n - mean * mean, 0.f);
  const float sc = bnw[c] * rsqrtf(var + 1e-5f);
  const float sh = bnb[c] - mean * sc;
  const float4 y = *(const float4*)(y0 + i);
  const float4 xv = *(const float4*)(x + i);
  float4 r;
  r.x = y.x * sc + sh + xv.x;
  r.y = y.y * sc + sh + xv.y;
  r.z = y.z * sc + sh + xv.z;
  r.w = y.w * sc + sh + xv.w;
  *(float4*)(out + i) = r;
}

// ---------------------------------------------------------------------------
extern "C" void kernel_launch(void* const* d_in, const int* in_sizes, int n_in,
                              void* d_out, int out_size, void* d_ws, size_t ws_size,
                              hipStream_t stream)
{
  (void)in_sizes; (void)n_in; (void)out_size; (void)ws_size;
  const float* x   = (const float*)d_in[0];
  const float* qw  = (const float*)d_in[1];
  const float* kw  = (const float*)d_in[2];
  const float* vw  = (const float*)d_in[3];
  const float* vb  = (const float*)d_in[4];
  const float* gam = (const float*)d_in[5];
  const float* bnw = (const float*)d_in[6];
  const float* bnb = (const float*)d_in[7];

  char* ws = (char*)d_ws;
  f16*   qa  = (f16*)(ws);
  f16*   ka2 = (f16*)(ws + (2u << 20));
  f16*   va3 = (f16*)(ws + (4u << 20));
  float* y0  = (float*)(ws + (6u << 20));
  float* gs1 = (float*)(ws + (10u << 20));          // 64 floats
  float* gs2 = (float*)(ws + (10u << 20) + 256);    // 64 floats (contiguous)

  // one-time opt-in for 64 KB dynamic LDS on pam_attn (host-side config)
  static bool lds_init = false;
  if (!lds_init) {
    (void)hipFuncSetAttribute((const void*)pam_attn,
                              hipFuncAttributeMaxDynamicSharedMemorySize, 65536);
    lds_init = true;
  }

  pam_pre  <<<1024, 256, 0, stream>>>(x, qw, kw, vw, vb, qa, ka2, va3, gs1);
  pam_attn <<<512, 512, 65536, stream>>>(qa, ka2, va3, gam, y0, gs1, gs2);
  pam_apply<<<1024, 256, 0, stream>>>(y0, x, gs1, gs2, bnw, bnb, (float*)d_out);
}

// Round 6
// 147.236 us; speedup vs baseline: 1.1994x; 1.0939x over previous
//
#include <hip/hip_runtime.h>
#include <stdint.h>

using f16 = _Float16;

typedef _Float16 f16x8 __attribute__((ext_vector_type(8)));
typedef _Float16 f16x4 __attribute__((ext_vector_type(4)));
typedef float f32x4 __attribute__((ext_vector_type(4)));

#define LOG2E 1.44269504088896340736f

__device__ __forceinline__ f16 f2h(float f) { return (f16)f; }  // RNE

#if __has_builtin(__builtin_amdgcn_exp2f)
__device__ __forceinline__ float fexp2(float x) { return __builtin_amdgcn_exp2f(x); }
#else
__device__ __forceinline__ float fexp2(float x) { return exp2f(x); }
#endif

typedef __attribute__((address_space(1))) const uint32_t gu32;
typedef __attribute__((address_space(3))) uint32_t lu32;

__device__ __forceinline__ void dma16(const void* g, void* l) {
  // global->LDS DMA, 16 B/lane. Global source is PER-LANE (caller includes
  // lane*16B); LDS dest is wave-uniform base + lane*16 auto-stride.
  __builtin_amdgcn_global_load_lds((gu32*)g, (lu32*)l, 16, 0, 0);
}

__device__ __forceinline__ f16x8 cvt8(const float* p) {
  const float4 a = *(const float4*)p;
  const float4 b = *(const float4*)(p + 4);
  f16x8 r;
  r[0] = (f16)a.x; r[1] = (f16)a.y; r[2] = (f16)a.z; r[3] = (f16)a.w;
  r[4] = (f16)b.x; r[5] = (f16)b.y; r[6] = (f16)b.z; r[7] = (f16)b.w;
  return r;
}

// B=4, C=64, N=4096.  Global in/out FP32; internal tensor-core path FP16.
// ws layout (bytes):
//   0     qa  f16 [4][4096][64]      (2 MB)  q*log2e, position-major
//   2 MB  ka2 f16 [4][8][4096][8]    (2 MB)  K: [b][c8][key'][8c], key' = key
//                                            ^ ((key>>3&1)<<2 | (key>>4&1))
//                                            (both-sides bank-conflict fix)
//   4 MB  va3 f16 [4][512][64][8]    (2 MB)  V key-chunked: [b][k8][c][8k]
//   6 MB  y0  f32 [4][64][4096]      (4 MB)  gamma*attn_out, pre-BN
//   10 MB stats: gs1[64] | gs2[64]   (zeroed by pre block 0)

// ---------------------------------------------------------------------------
// pre v2: vectorized.  256 blocks x 256 thr, 64-position tiles.
//  - conv writes are f16x8 (16B) stores, coalesced per wave (qa: 1KB
//    contiguous/wave-store; ka2: 128B-contiguous per 8-lane group).
//  - conv reads: 1 ds_read_b128 + 2 scalar edge reads (was 30 scalars).
//  - V projection computes v^T (A=x^T rows, B=vw cols) so C-layout rows are
//    4 consecutive n -> f16x4 va3 stores (was 16 scalar 2B stores).
// ---------------------------------------------------------------------------
__global__ __launch_bounds__(256, 2) void pam_pre(
    const float* __restrict__ x, const float* __restrict__ qw,
    const float* __restrict__ kw, const float* __restrict__ vw,
    const float* __restrict__ vb,
    f16* __restrict__ qa, f16* __restrict__ ka2, f16* __restrict__ va3,
    float* __restrict__ gz)
{
  __shared__ alignas(16) f16 xt[64 * 72];   // xt[n][c] f16, row stride 72
  const int tid = threadIdx.x;
  const int b = blockIdx.x >> 6;
  const int n0 = (blockIdx.x & 63) << 6;
  const int lane = tid & 63;
  const int wv = tid >> 6;
  const int quad = lane >> 4, l15 = lane & 15;

  if (blockIdx.x == 0 && tid < 128) gz[tid] = 0.f;   // gs1|gs2 zero-init

  // stage x[b][c][n0:+64] (fp32) transposed into xt[n][c] (f16)
  {
    const int c = tid >> 2;
    const int j0 = (tid & 3) << 4;
    const float* xp = x + ((size_t)(b * 64 + c) << 12) + n0 + j0;
#pragma unroll
    for (int j = 0; j < 4; ++j) {
      const float4 v0 = *(const float4*)(xp + j * 4);
      const int n = j0 + j * 4;
      xt[(n + 0) * 72 + c] = f2h(v0.x);
      xt[(n + 1) * 72 + c] = f2h(v0.y);
      xt[(n + 2) * 72 + c] = f2h(v0.z);
      xt[(n + 3) * 72 + c] = f2h(v0.w);
    }
  }
  __syncthreads();

  // conv over channel axis (SAME, zero pad), 8 channels per thread-step
  const float qw0 = qw[0], qw1 = qw[1], qw2 = qw[2];
  const float kw0 = kw[0], kw1 = kw[1], kw2 = kw[2];
#pragma unroll
  for (int i = 0; i < 2; ++i) {
    const int n = (tid >> 3) + i * 32;
    const int c8 = tid & 7;
    const f16x8 v0 = *(const f16x8*)&xt[n * 72 + c8 * 8];
    const float lm = (c8 > 0) ? (float)xt[n * 72 + c8 * 8 - 1] : 0.f;
    const float rp = (c8 < 7) ? (float)xt[n * 72 + c8 * 8 + 8] : 0.f;
    f16x8 qv8, kv8;
#pragma unroll
    for (int j = 0; j < 8; ++j) {
      const float xm = (j == 0) ? lm : (float)v0[j - 1];
      const float x0 = (float)v0[j];
      const float xp = (j == 7) ? rp : (float)v0[j + 1];
      qv8[j] = f2h((qw0 * xm + qw1 * x0 + qw2 * xp) * LOG2E);  // log2-domain
      kv8[j] = f2h(kw0 * xm + kw1 * x0 + kw2 * xp);
    }
    const int nn = n0 + n;
    *(f16x8*)(qa + ((size_t)((b << 12) + nn) << 6) + c8 * 8) = qv8;
    // bank-fix storage permutation: flip key bits [2],[0] by bits [3],[4]
    const int np = nn ^ ((((nn >> 3) & 1) << 2) | ((nn >> 4) & 1));
    *(f16x8*)(ka2 + (((size_t)(b * 8 + c8)) << 15) + (np << 3)) = kv8;
  }

  // v^T[n][co] = (vw @ x)^T + vb via mfma; wave wv -> n rows [16wv,+16)
  {
    const f16x8 a0 = *(const f16x8*)&xt[(wv * 16 + l15) * 72 + quad * 8];
    const f16x8 a1 = *(const f16x8*)&xt[(wv * 16 + l15) * 72 + quad * 8 + 32];
    const int nb = n0 + wv * 16 + quad * 4;      // 4 consecutive n per thread
#pragma unroll
    for (int ct = 0; ct < 4; ++ct) {
      const int co = ct * 16 + l15;
      const f16x8 b0 = cvt8(vw + co * 64 + quad * 8);
      const f16x8 b1 = cvt8(vw + co * 64 + quad * 8 + 32);
      f32x4 z = {0.f, 0.f, 0.f, 0.f};
      z = __builtin_amdgcn_mfma_f32_16x16x32_f16(a0, b0, z, 0, 0, 0);
      z = __builtin_amdgcn_mfma_f32_16x16x32_f16(a1, b1, z, 0, 0, 0);
      const float vbv = vb[co];
      f16x4 pv;
#pragma unroll
      for (int r = 0; r < 4; ++r) pv[r] = f2h(z[r] + vbv);
      // va3[b][nb>>3][co][nb&7], nb&7 in {0,4} -> 8B-aligned f16x4 store
      *(f16x4*)(va3 + (((size_t)(b * 512 + (nb >> 3))) << 9)
                + (co << 3) + (nb & 7)) = pv;
    }
  }
}

// ---------------------------------------------------------------------------
// attention v21 = r2's v18 verbatim (the measured-best structure: 512 thr,
// 8 waves, 128-key DMA double-buffer, 1 barrier/iter, 2 blocks/CU) with one
// surgical change: the K-gather bank fix.  ka2 is stored XOR-permuted
// (pam_pre) and the gather XORs the same mask -> each 16-lane b128 phase
// spreads over all 8 16B bank-slots (2-way, free) instead of 4-way.
// Dataflow: K-perm gather makes S^T regs land in PV B-frag k-order
// (zero-shuffle P); O^T PV via 16x16x32; lane-local softmax + defer-max.
// ---------------------------------------------------------------------------
__global__ __launch_bounds__(512, 2) void pam_attn(
    const f16* __restrict__ qa, const f16* __restrict__ ka2,
    const f16* __restrict__ va3, const float* __restrict__ gam,
    float* __restrict__ y0, float* __restrict__ gs1, float* __restrict__ gs2)
{
  __shared__ alignas(16) f16 kbuf[2][8192];   // [c8][128key'][8c], 16 KB each
  __shared__ alignas(16) f16 vbuf[2][8192];   // [16 k8][64 c][8 k], 16 KB each
  __shared__ float ldsO[32 * 65];             // [q][c], pad 65
  __shared__ float ldsM[4][32], ldsL[4][32], ldsMg[32], ldsInv[32];

  const int tid = threadIdx.x;
  const int wv = tid >> 6, lane = tid & 63;
  const int quad = lane >> 4, l15 = lane & 15;
  const int ks = wv & 3, qh = wv >> 2;
  const int b = blockIdx.x & 3;
  const int qb = blockIdx.x >> 2;          // 0..127
  const int qb0 = qb << 5;
  const int phase = qb & 31;               // anti-convoy rotation (32 tiles)

  for (int i = tid; i < 32 * 65; i += 512) ldsO[i] = 0.f;

  const int bn = b << 12;
  // Q fragments (B-operand: col=l15=q, k=quad*8+j over channels)
  f16x8 bq0, bq1;
  {
    const int q = qb0 + qh * 16 + l15;
    const f16* qp = qa + ((size_t)(bn + q) << 6) + quad * 8;
    bq0 = *(const f16x8*)qp;
    bq1 = *(const f16x8*)(qp + 32);
  }

  // staging bases (PER-LANE source: + lane*8 f16 = 16 B/lane).
  // K: wave wv stages c8-group wv (128 keys x 8c = 2 KB per tile).
  // V: wave wv stages k8-chunks {2wv, 2wv+1} (2 x 1 KB per tile).
  const f16* kg0 = ka2 + (((size_t)(b * 8 + wv)) << 15) + (lane << 3);
  const f16* vg0 = va3 + ((size_t)b << 18) + (wv << 10) + (lane << 3);

  f32x4 o[4] = {};                 // O^T: col=l15=q, row c = ct*16+quad*4+r
  float m = -1e30f, lp = 0.f;

  // stage tile 'phase' into buf 0
  dma16(kg0 + ((size_t)phase << 10),       kbuf[0] + (wv << 10));
  dma16(kg0 + ((size_t)phase << 10) + 512, kbuf[0] + (wv << 10) + 512);
  dma16(vg0 + ((size_t)phase << 13),       vbuf[0] + (wv << 10));
  dma16(vg0 + ((size_t)phase << 13) + 512, vbuf[0] + (wv << 10) + 512);
  __syncthreads();

  // K gather with both-sides XOR: want tile-local key pos_t; it is stored at
  // pos_t ^ mask(pos_t), mask = (bit3<<2)|bit4.  S^T reg r of quad then holds
  // key ks*32 + quad*8 + t*4 + r == PV k-order (zero-shuffle P).
  const int u = l15 >> 2;
  const int xmsk = ((u & 1) << 2) | (u >> 1);
  const int pos0 = (ks << 5) + (u << 3) + (l15 & 3);
  const int koff0 = (pos0 ^ xmsk) << 3;
  const int koff1 = koff0 ^ 32;                // (pos0+4)^mask, same mask
  const int vbase = ((ks * 4 + quad) << 9) + (l15 << 3);

#pragma unroll 1
  for (int kt = 0; kt < 32; ++kt) {
    const int cur = kt & 1;
    {
      const int tn = (kt + 1 + phase) & 31;
      f16* kd = kbuf[cur ^ 1] + (wv << 10);
      f16* vd = vbuf[cur ^ 1] + (wv << 10);
      dma16(kg0 + ((size_t)tn << 10),       kd);
      dma16(kg0 + ((size_t)tn << 10) + 512, kd + 512);
      dma16(vg0 + ((size_t)tn << 13),       vd);
      dma16(vg0 + ((size_t)tn << 13) + 512, vd + 512);
    }

    const f16* kc = kbuf[cur];
    const f16* vc = vbuf[cur];
    const f16x8 ak00 = *(const f16x8*)(kc + (quad << 10) + koff0);
    const f16x8 ak01 = *(const f16x8*)(kc + ((4 + quad) << 10) + koff0);
    const f16x8 ak10 = *(const f16x8*)(kc + (quad << 10) + koff1);
    const f16x8 ak11 = *(const f16x8*)(kc + ((4 + quad) << 10) + koff1);

    // S^T[32 key (permuted)][16 q], contraction over 64 channels
    f32x4 z0, z1;
    {
      f32x4 z = {0.f, 0.f, 0.f, 0.f};
      z = __builtin_amdgcn_mfma_f32_16x16x32_f16(ak00, bq0, z, 0, 0, 0);
      z0 = __builtin_amdgcn_mfma_f32_16x16x32_f16(ak01, bq1, z, 0, 0, 0);
    }
    {
      f32x4 z = {0.f, 0.f, 0.f, 0.f};
      z = __builtin_amdgcn_mfma_f32_16x16x32_f16(ak10, bq0, z, 0, 0, 0);
      z1 = __builtin_amdgcn_mfma_f32_16x16x32_f16(ak11, bq1, z, 0, 0, 0);
    }

    // online softmax: lane holds keys quad*8+{0..7} for query q=l15
    float tmax = fmaxf(fmaxf(fmaxf(z0[0], z0[1]), fmaxf(z0[2], z0[3])),
                       fmaxf(fmaxf(z1[0], z1[1]), fmaxf(z1[2], z1[3])));
    tmax = fmaxf(tmax, __shfl_xor(tmax, 16, 64));
    tmax = fmaxf(tmax, __shfl_xor(tmax, 32, 64));
    const bool need = !__all(tmax <= m + 8.f);    // defer-max, THR=8
    const float mn = need ? fmaxf(m, tmax) : m;

    const float p0 = fexp2(z0[0] - mn);
    const float p1 = fexp2(z0[1] - mn);
    const float p2 = fexp2(z0[2] - mn);
    const float p3 = fexp2(z0[3] - mn);
    const float p4 = fexp2(z1[0] - mn);
    const float p5 = fexp2(z1[1] - mn);
    const float p6 = fexp2(z1[2] - mn);
    const float p7 = fexp2(z1[3] - mn);
    const float ts = ((p0 + p1) + (p2 + p3)) + ((p4 + p5) + (p6 + p7));

    f16x8 pa;   // P^T B-frag: k-order == reg order (by K permutation)
    pa[0] = f2h(p0); pa[1] = f2h(p1); pa[2] = f2h(p2); pa[3] = f2h(p3);
    pa[4] = f2h(p4); pa[5] = f2h(p5); pa[6] = f2h(p6); pa[7] = f2h(p7);

    if (need) {
      const float al = fexp2(m - mn);   // lane-local (q in column)
      lp = lp * al + ts;
      m = mn;
#pragma unroll
      for (int ct = 0; ct < 4; ++ct)
        for (int r = 0; r < 4; ++r) o[ct][r] *= al;
    } else {
      lp += ts;
    }

    // O^T += V * P^T : one K=32 MFMA per 16-channel tile
#pragma unroll
    for (int ct = 0; ct < 4; ++ct) {
      const f16x8 av = *(const f16x8*)(vc + vbase + ct * 128);
      o[ct] = __builtin_amdgcn_mfma_f32_16x16x32_f16(av, pa, o[ct], 0, 0, 0);
    }
    __syncthreads();   // DMA landed + all waves done with buffers
  }

  // publish per-wave online state (m quad-uniform; lp reduced across quads)
  {
    float v = lp;
    v += __shfl_xor(v, 16, 64);
    v += __shfl_xor(v, 32, 64);
    if (quad == 0) {
      ldsM[ks][qh * 16 + l15] = m;
      ldsL[ks][qh * 16 + l15] = v;
    }
  }
  __syncthreads();

  // per-query global max + denom (4 key-slices)
  if (tid < 32) {
    const float M = fmaxf(fmaxf(ldsM[0][tid], ldsM[1][tid]),
                          fmaxf(ldsM[2][tid], ldsM[3][tid]));
    const float lt = ldsL[0][tid] * fexp2(ldsM[0][tid] - M) +
                     ldsL[1][tid] * fexp2(ldsM[1][tid] - M) +
                     ldsL[2][tid] * fexp2(ldsM[2][tid] - M) +
                     ldsL[3][tid] * fexp2(ldsM[3][tid] - M);
    ldsMg[tid] = M;
    ldsInv[tid] = 1.f / lt;
  }
  __syncthreads();

  // m-aware merge of partial O^T across the 4 key-split waves (sc lane-local)
  {
    const int q = qh * 16 + l15;
    const float sc = fexp2(m - ldsMg[q]);
#pragma unroll
    for (int ct = 0; ct < 4; ++ct)
      for (int r = 0; r < 4; ++r)
        atomicAdd(&ldsO[q * 65 + ct * 16 + quad * 4 + r], o[ct][r] * sc);
  }
  __syncthreads();

  // epilogue: y0[b][c][n] = gamma * O / l ; BN partial sums
  const float g = gam[0];
  {
    const int c = tid >> 3;              // 0..63
    const int q0 = (tid & 7) << 2;       // 0..28
    float4 v4;
    float* vp = &v4.x;
    float s1 = 0.f, s2 = 0.f;
    for (int r = 0; r < 4; ++r) {
      const float val = g * ldsO[(q0 + r) * 65 + c] * ldsInv[q0 + r];
      vp[r] = val; s1 += val; s2 += val * val;
    }
    *(float4*)(y0 + ((size_t)(b * 64 + c) << 12) + qb0 + q0) = v4;
    s1 += __shfl_xor(s1, 1, 64);
    s2 += __shfl_xor(s2, 1, 64);
    s1 += __shfl_xor(s1, 2, 64);
    s2 += __shfl_xor(s2, 2, 64);
    s1 += __shfl_xor(s1, 4, 64);
    s2 += __shfl_xor(s2, 4, 64);
    if ((tid & 7) == 0) {
      atomicAdd(&gs1[c], s1);
      atomicAdd(&gs2[c], s2);
    }
  }
}

// ---------------------------------------------------------------------------
// apply: BN(scale/shift from gs1/gs2) + residual.
// ---------------------------------------------------------------------------
__global__ __launch_bounds__(256, 2) void pam_apply(
    const float* __restrict__ y0, const float* __restrict__ x,
    const float* __restrict__ gs1, const float* __restrict__ gs2,
    const float* __restrict__ bnw, const float* __restrict__ bnb,
    float* __restrict__ out)
{
  const int i = (blockIdx.x * 256 + threadIdx.x) << 2;   // 4 elems/thread
  const int c = (i >> 12) & 63;
  const float inv_n = 1.f / 16384.f;
  const float mean = gs1[c] * inv_n;
  const float var = fmaxf(gs2[c] * inv_n - mean * mean, 0.f);
  const float sc = bnw[c] * rsqrtf(var + 1e-5f);
  const float sh = bnb[c] - mean * sc;
  const float4 y = *(const float4*)(y0 + i);
  const float4 xv = *(const float4*)(x + i);
  float4 r;
  r.x = y.x * sc + sh + xv.x;
  r.y = y.y * sc + sh + xv.y;
  r.z = y.z * sc + sh + xv.z;
  r.w = y.w * sc + sh + xv.w;
  *(float4*)(out + i) = r;
}

// ---------------------------------------------------------------------------
extern "C" void kernel_launch(void* const* d_in, const int* in_sizes, int n_in,
                              void* d_out, int out_size, void* d_ws, size_t ws_size,
                              hipStream_t stream)
{
  (void)in_sizes; (void)n_in; (void)out_size; (void)ws_size;
  const float* x   = (const float*)d_in[0];
  const float* qw  = (const float*)d_in[1];
  const float* kw  = (const float*)d_in[2];
  const float* vw  = (const float*)d_in[3];
  const float* vb  = (const float*)d_in[4];
  const float* gam = (const float*)d_in[5];
  const float* bnw = (const float*)d_in[6];
  const float* bnb = (const float*)d_in[7];

  char* ws = (char*)d_ws;
  f16*   qa  = (f16*)(ws);
  f16*   ka2 = (f16*)(ws + (2u << 20));
  f16*   va3 = (f16*)(ws + (4u << 20));
  float* y0  = (float*)(ws + (6u << 20));
  float* gs1 = (float*)(ws + (10u << 20));          // 64 floats
  float* gs2 = (float*)(ws + (10u << 20) + 256);    // 64 floats (contiguous)

  pam_pre  <<<256, 256, 0, stream>>>(x, qw, kw, vw, vb, qa, ka2, va3, gs1);
  pam_attn <<<512, 512, 0, stream>>>(qa, ka2, va3, gam, y0, gs1, gs2);
  pam_apply<<<1024, 256, 0, stream>>>(y0, x, gs1, gs2, bnw, bnb, (float*)d_out);
}

// Round 7
// 147.032 us; speedup vs baseline: 1.2011x; 1.0014x over previous
//
#include <hip/hip_runtime.h>
#include <stdint.h>

using f16 = _Float16;

typedef _Float16 f16x8 __attribute__((ext_vector_type(8)));
typedef _Float16 f16x4 __attribute__((ext_vector_type(4)));
typedef float f32x4 __attribute__((ext_vector_type(4)));

#define LOG2E 1.44269504088896340736f

__device__ __forceinline__ f16 f2h(float f) { return (f16)f; }  // RNE

#if __has_builtin(__builtin_amdgcn_exp2f)
__device__ __forceinline__ float fexp2(float x) { return __builtin_amdgcn_exp2f(x); }
#else
__device__ __forceinline__ float fexp2(float x) { return exp2f(x); }
#endif

typedef __attribute__((address_space(1))) const uint32_t gu32;
typedef __attribute__((address_space(3))) uint32_t lu32;

__device__ __forceinline__ void dma16(const void* g, void* l) {
  // global->LDS DMA, 16 B/lane. Global source is PER-LANE (caller includes
  // lane*16B); LDS dest is wave-uniform base + lane*16 auto-stride.
  __builtin_amdgcn_global_load_lds((gu32*)g, (lu32*)l, 16, 0, 0);
}

__device__ __forceinline__ f16x8 cvt8(const float* p) {
  const float4 a = *(const float4*)p;
  const float4 b = *(const float4*)(p + 4);
  f16x8 r;
  r[0] = (f16)a.x; r[1] = (f16)a.y; r[2] = (f16)a.z; r[3] = (f16)a.w;
  r[4] = (f16)b.x; r[5] = (f16)b.y; r[6] = (f16)b.z; r[7] = (f16)b.w;
  return r;
}

// B=4, C=64, N=4096.  Global in/out FP32; internal tensor-core path FP16.
// ws layout (bytes):
//   0     qa  f16 [4][4096][64]      (2 MB)  q*log2e, position-major
//   2 MB  ka2 f16 [4][8][4096][8]    (2 MB)  K: [b][c8][key'][8c], key' = key
//                                            ^ ((key>>3&1)<<2 | (key>>4&1))
//   4 MB  va3 f16 [4][512][64][8]    (2 MB)  V key-chunked: [b][k8][c][8k]
//   6 MB  y0  f32 [4][64][4096]      (4 MB)  gamma*attn_out, pre-BN
//   10 MB stats: gs1[64] | gs2[64]   (zeroed by pre block 0)

// ---------------------------------------------------------------------------
// pre v3: vectorized I/O (r6) at restored parallelism (r2's grid).
// 1024 blocks x 256 thr, 16-position tiles, 4 blocks/CU.
//  - conv: 128 threads, 1 ds_read_b128 + 2 edge scalars -> f16x8 q/k stores.
//  - V-proj: wave wv computes co-columns [16wv,+16) of v^T via 2 MFMAs;
//    C rows are 4 consecutive n -> f16x4 va3 stores.
// ---------------------------------------------------------------------------
__global__ __launch_bounds__(256, 2) void pam_pre(
    const float* __restrict__ x, const float* __restrict__ qw,
    const float* __restrict__ kw, const float* __restrict__ vw,
    const float* __restrict__ vb,
    f16* __restrict__ qa, f16* __restrict__ ka2, f16* __restrict__ va3,
    float* __restrict__ gz)
{
  __shared__ alignas(16) f16 xt[16 * 72];   // xt[n][c] f16, row stride 72
  const int tid = threadIdx.x;
  const int b = blockIdx.x >> 8;
  const int n0 = (blockIdx.x & 255) << 4;
  const int lane = tid & 63;
  const int wv = tid >> 6;
  const int quad = lane >> 4, l15 = lane & 15;

  if (blockIdx.x == 0 && tid < 128) gz[tid] = 0.f;   // gs1|gs2 zero-init

  // stage x[b][c][n0:+16] (fp32) transposed into xt[n][c] (f16)
  {
    const int c = tid >> 2;
    const int j0 = (tid & 3) << 2;
    const float4 v0 = *(const float4*)(x + ((size_t)(b * 64 + c) << 12) + n0 + j0);
    xt[(j0 + 0) * 72 + c] = f2h(v0.x);
    xt[(j0 + 1) * 72 + c] = f2h(v0.y);
    xt[(j0 + 2) * 72 + c] = f2h(v0.z);
    xt[(j0 + 3) * 72 + c] = f2h(v0.w);
  }
  __syncthreads();

  // conv over channel axis (SAME, zero pad): 128 threads, 8 channels each
  if (tid < 128) {
    const float qw0 = qw[0], qw1 = qw[1], qw2 = qw[2];
    const float kw0 = kw[0], kw1 = kw[1], kw2 = kw[2];
    const int n = tid >> 3;            // 0..15
    const int c8 = tid & 7;            // 0..7
    const f16x8 v0 = *(const f16x8*)&xt[n * 72 + c8 * 8];
    const float lm = (c8 > 0) ? (float)xt[n * 72 + c8 * 8 - 1] : 0.f;
    const float rp = (c8 < 7) ? (float)xt[n * 72 + c8 * 8 + 8] : 0.f;
    f16x8 qv8, kv8;
#pragma unroll
    for (int j = 0; j < 8; ++j) {
      const float xm = (j == 0) ? lm : (float)v0[j - 1];
      const float x0 = (float)v0[j];
      const float xp = (j == 7) ? rp : (float)v0[j + 1];
      qv8[j] = f2h((qw0 * xm + qw1 * x0 + qw2 * xp) * LOG2E);  // log2-domain
      kv8[j] = f2h(kw0 * xm + kw1 * x0 + kw2 * xp);
    }
    const int nn = n0 + n;
    *(f16x8*)(qa + ((size_t)((b << 12) + nn) << 6) + c8 * 8) = qv8;
    // bank-fix storage permutation: flip key bits [2],[0] by bits [3],[4]
    const int np = nn ^ ((((nn >> 3) & 1) << 2) | ((nn >> 4) & 1));
    *(f16x8*)(ka2 + (((size_t)(b * 8 + c8)) << 15) + (np << 3)) = kv8;
  }

  // v^T[n][co] via mfma; wave wv -> co columns [16wv,+16)
  {
    const f16x8 a0 = *(const f16x8*)&xt[l15 * 72 + quad * 8];
    const f16x8 a1 = *(const f16x8*)&xt[l15 * 72 + quad * 8 + 32];
    const int co = wv * 16 + l15;
    const f16x8 b0 = cvt8(vw + co * 64 + quad * 8);
    const f16x8 b1 = cvt8(vw + co * 64 + quad * 8 + 32);
    f32x4 z = {0.f, 0.f, 0.f, 0.f};
    z = __builtin_amdgcn_mfma_f32_16x16x32_f16(a0, b0, z, 0, 0, 0);
    z = __builtin_amdgcn_mfma_f32_16x16x32_f16(a1, b1, z, 0, 0, 0);
    const float vbv = vb[co];
    f16x4 pv;
#pragma unroll
    for (int r = 0; r < 4; ++r) pv[r] = f2h(z[r] + vbv);
    const int nb = n0 + quad * 4;      // 4 consecutive n per thread
    // va3[b][nb>>3][co][nb&7], nb&7 in {0,4} -> 8B-aligned f16x4 store
    *(f16x4*)(va3 + (((size_t)(b * 512 + (nb >> 3))) << 9)
              + (co << 3) + (nb & 7)) = pv;
  }
}

// ---------------------------------------------------------------------------
// attention v22 = r6 skeleton (512 thr, 8 waves, 128-key K double-buffer,
// 1 barrier/iter) with V staging REMOVED (guide common-mistake #7: V is
// L2-resident, 2x-reused -> staging was overhead):
//  - V fragments load global->VGPR, issued at iteration TOP, consumed at PV
//    ~500 cy later (QK^T + softmax cover the ~200 cy L2 latency).
//  - barrier drain halves (2 dma16/wave-iter instead of 4).
//  - LDS 75 -> ~42 KB; __launch_bounds__(512,6) targets 3 blocks/CU
//    (24 waves/CU) for a third overlapping barrier domain.
// Dataflow unchanged: XOR K-perm gather -> S^T regs in PV B-frag k-order
// (zero-shuffle P); O^T PV via 16x16x32; lane-local softmax + defer-max.
// ---------------------------------------------------------------------------
__global__ __launch_bounds__(512, 6) void pam_attn(
    const f16* __restrict__ qa, const f16* __restrict__ ka2,
    const f16* __restrict__ va3, const float* __restrict__ gam,
    float* __restrict__ y0, float* __restrict__ gs1, float* __restrict__ gs2)
{
  __shared__ alignas(16) f16 kbuf[2][8192];   // [c8][128key'][8c], 16 KB each
  __shared__ float ldsO[32 * 65];             // [q][c], pad 65
  __shared__ float ldsM[4][32], ldsL[4][32], ldsMg[32], ldsInv[32];

  const int tid = threadIdx.x;
  const int wv = tid >> 6, lane = tid & 63;
  const int quad = lane >> 4, l15 = lane & 15;
  const int ks = wv & 3, qh = wv >> 2;
  const int b = blockIdx.x & 3;
  const int qb = blockIdx.x >> 2;          // 0..127
  const int qb0 = qb << 5;
  const int phase = qb & 31;               // anti-convoy rotation (32 tiles)

  for (int i = tid; i < 32 * 65; i += 512) ldsO[i] = 0.f;

  const int bn = b << 12;
  // Q fragments (B-operand: col=l15=q, k=quad*8+j over channels)
  f16x8 bq0, bq1;
  {
    const int q = qb0 + qh * 16 + l15;
    const f16* qp = qa + ((size_t)(bn + q) << 6) + quad * 8;
    bq0 = *(const f16x8*)qp;
    bq1 = *(const f16x8*)(qp + 32);
  }

  // K staging base (PER-LANE source: + lane*8 f16 = 16 B/lane).
  // wave wv stages c8-group wv (128 keys x 8c = 2 KB per tile).
  const f16* kg0 = ka2 + (((size_t)(b * 8 + wv)) << 15) + (lane << 3);
  // V per-lane global base: va3[b][k8 = 16*g + ks*4 + quad][c][8k], +l15*8
  const f16* vgp = va3 + ((size_t)b << 18) + ((ks * 4 + quad) << 9) + (l15 << 3);

  f32x4 o[4] = {};                 // O^T: col=l15=q, row c = ct*16+quad*4+r
  float m = -1e30f, lp = 0.f;

  // stage K tile 'phase' into buf 0
  dma16(kg0 + ((size_t)phase << 10),       kbuf[0] + (wv << 10));
  dma16(kg0 + ((size_t)phase << 10) + 512, kbuf[0] + (wv << 10) + 512);
  __syncthreads();

  // K gather with both-sides XOR: S^T reg r of quad holds key
  // ks*32 + quad*8 + t*4 + r == PV k-order (zero-shuffle P).
  const int u = l15 >> 2;
  const int xmsk = ((u & 1) << 2) | (u >> 1);
  const int pos0 = (ks << 5) + (u << 3) + (l15 & 3);
  const int koff0 = (pos0 ^ xmsk) << 3;
  const int koff1 = koff0 ^ 32;                // (pos0+4)^mask, same mask

#pragma unroll 1
  for (int kt = 0; kt < 32; ++kt) {
    const int cur = kt & 1;
    const int gcur = (kt + phase) & 31;

    // V fragments for THIS tile: global loads issued first, used at PV
    const f16* vt = vgp + ((size_t)gcur << 13);
    const f16x8 av0 = *(const f16x8*)(vt);
    const f16x8 av1 = *(const f16x8*)(vt + 128);
    const f16x8 av2 = *(const f16x8*)(vt + 256);
    const f16x8 av3 = *(const f16x8*)(vt + 384);

    // prefetch K tile kt+1
    {
      const int tn = (kt + 1 + phase) & 31;
      f16* kd = kbuf[cur ^ 1] + (wv << 10);
      dma16(kg0 + ((size_t)tn << 10),       kd);
      dma16(kg0 + ((size_t)tn << 10) + 512, kd + 512);
    }

    const f16* kc = kbuf[cur];
    const f16x8 ak00 = *(const f16x8*)(kc + (quad << 10) + koff0);
    const f16x8 ak01 = *(const f16x8*)(kc + ((4 + quad) << 10) + koff0);
    const f16x8 ak10 = *(const f16x8*)(kc + (quad << 10) + koff1);
    const f16x8 ak11 = *(const f16x8*)(kc + ((4 + quad) << 10) + koff1);

    // S^T[32 key (permuted)][16 q], contraction over 64 channels
    f32x4 z0, z1;
    {
      f32x4 z = {0.f, 0.f, 0.f, 0.f};
      z = __builtin_amdgcn_mfma_f32_16x16x32_f16(ak00, bq0, z, 0, 0, 0);
      z0 = __builtin_amdgcn_mfma_f32_16x16x32_f16(ak01, bq1, z, 0, 0, 0);
    }
    {
      f32x4 z = {0.f, 0.f, 0.f, 0.f};
      z = __builtin_amdgcn_mfma_f32_16x16x32_f16(ak10, bq0, z, 0, 0, 0);
      z1 = __builtin_amdgcn_mfma_f32_16x16x32_f16(ak11, bq1, z, 0, 0, 0);
    }

    // online softmax: lane holds keys quad*8+{0..7} for query q=l15
    float tmax = fmaxf(fmaxf(fmaxf(z0[0], z0[1]), fmaxf(z0[2], z0[3])),
                       fmaxf(fmaxf(z1[0], z1[1]), fmaxf(z1[2], z1[3])));
    tmax = fmaxf(tmax, __shfl_xor(tmax, 16, 64));
    tmax = fmaxf(tmax, __shfl_xor(tmax, 32, 64));
    const bool need = !__all(tmax <= m + 8.f);    // defer-max, THR=8
    const float mn = need ? fmaxf(m, tmax) : m;

    const float p0 = fexp2(z0[0] - mn);
    const float p1 = fexp2(z0[1] - mn);
    const float p2 = fexp2(z0[2] - mn);
    const float p3 = fexp2(z0[3] - mn);
    const float p4 = fexp2(z1[0] - mn);
    const float p5 = fexp2(z1[1] - mn);
    const float p6 = fexp2(z1[2] - mn);
    const float p7 = fexp2(z1[3] - mn);
    const float ts = ((p0 + p1) + (p2 + p3)) + ((p4 + p5) + (p6 + p7));

    f16x8 pa;   // P^T B-frag: k-order == reg order (by K permutation)
    pa[0] = f2h(p0); pa[1] = f2h(p1); pa[2] = f2h(p2); pa[3] = f2h(p3);
    pa[4] = f2h(p4); pa[5] = f2h(p5); pa[6] = f2h(p6); pa[7] = f2h(p7);

    if (need) {
      const float al = fexp2(m - mn);   // lane-local (q in column)
      lp = lp * al + ts;
      m = mn;
#pragma unroll
      for (int ct = 0; ct < 4; ++ct)
        for (int r = 0; r < 4; ++r) o[ct][r] *= al;
    } else {
      lp += ts;
    }

    // O^T += V * P^T : one K=32 MFMA per 16-channel tile (V from registers)
    o[0] = __builtin_amdgcn_mfma_f32_16x16x32_f16(av0, pa, o[0], 0, 0, 0);
    o[1] = __builtin_amdgcn_mfma_f32_16x16x32_f16(av1, pa, o[1], 0, 0, 0);
    o[2] = __builtin_amdgcn_mfma_f32_16x16x32_f16(av2, pa, o[2], 0, 0, 0);
    o[3] = __builtin_amdgcn_mfma_f32_16x16x32_f16(av3, pa, o[3], 0, 0, 0);
    __syncthreads();   // K DMA landed + all waves done with kbuf
  }

  // publish per-wave online state (m quad-uniform; lp reduced across quads)
  {
    float v = lp;
    v += __shfl_xor(v, 16, 64);
    v += __shfl_xor(v, 32, 64);
    if (quad == 0) {
      ldsM[ks][qh * 16 + l15] = m;
      ldsL[ks][qh * 16 + l15] = v;
    }
  }
  __syncthreads();

  // per-query global max + denom (4 key-slices)
  if (tid < 32) {
    const float M = fmaxf(fmaxf(ldsM[0][tid], ldsM[1][tid]),
                          fmaxf(ldsM[2][tid], ldsM[3][tid]));
    const float lt = ldsL[0][tid] * fexp2(ldsM[0][tid] - M) +
                     ldsL[1][tid] * fexp2(ldsM[1][tid] - M) +
                     ldsL[2][tid] * fexp2(ldsM[2][tid] - M) +
                     ldsL[3][tid] * fexp2(ldsM[3][tid] - M);
    ldsMg[tid] = M;
    ldsInv[tid] = 1.f / lt;
  }
  __syncthreads();

  // m-aware merge of partial O^T across the 4 key-split waves (sc lane-local)
  {
    const int q = qh * 16 + l15;
    const float sc = fexp2(m - ldsMg[q]);
#pragma unroll
    for (int ct = 0; ct < 4; ++ct)
      for (int r = 0; r < 4; ++r)
        atomicAdd(&ldsO[q * 65 + ct * 16 + quad * 4 + r], o[ct][r] * sc);
  }
  __syncthreads();

  // epilogue: y0[b][c][n] = gamma * O / l ; BN partial sums
  const float g = gam[0];
  {
    const int c = tid >> 3;              // 0..63
    const int q0 = (tid & 7) << 2;       // 0..28
    float4 v4;
    float* vp = &v4.x;
    float s1 = 0.f, s2 = 0.f;
    for (int r = 0; r < 4; ++r) {
      const float val = g * ldsO[(q0 + r) * 65 + c] * ldsInv[q0 + r];
      vp[r] = val; s1 += val; s2 += val * val;
    }
    *(float4*)(y0 + ((size_t)(b * 64 + c) << 12) + qb0 + q0) = v4;
    s1 += __shfl_xor(s1, 1, 64);
    s2 += __shfl_xor(s2, 1, 64);
    s1 += __shfl_xor(s1, 2, 64);
    s2 += __shfl_xor(s2, 2, 64);
    s1 += __shfl_xor(s1, 4, 64);
    s2 += __shfl_xor(s2, 4, 64);
    if ((tid & 7) == 0) {
      atomicAdd(&gs1[c], s1);
      atomicAdd(&gs2[c], s2);
    }
  }
}

// ---------------------------------------------------------------------------
// apply: BN(scale/shift from gs1/gs2) + residual.
// ---------------------------------------------------------------------------
__global__ __launch_bounds__(256, 2) void pam_apply(
    const float* __restrict__ y0, const float* __restrict__ x,
    const float* __restrict__ gs1, const float* __restrict__ gs2,
    const float* __restrict__ bnw, const float* __restrict__ bnb,
    float* __restrict__ out)
{
  const int i = (blockIdx.x * 256 + threadIdx.x) << 2;   // 4 elems/thread
  const int c = (i >> 12) & 63;
  const float inv_n = 1.f / 16384.f;
  const float mean = gs1[c] * inv_n;
  const float var = fmaxf(gs2[c] * inv_n - mean * mean, 0.f);
  const float sc = bnw[c] * rsqrtf(var + 1e-5f);
  const float sh = bnb[c] - mean * sc;
  const float4 y = *(const float4*)(y0 + i);
  const float4 xv = *(const float4*)(x + i);
  float4 r;
  r.x = y.x * sc + sh + xv.x;
  r.y = y.y * sc + sh + xv.y;
  r.z = y.z * sc + sh + xv.z;
  r.w = y.w * sc + sh + xv.w;
  *(float4*)(out + i) = r;
}

// ---------------------------------------------------------------------------
extern "C" void kernel_launch(void* const* d_in, const int* in_sizes, int n_in,
                              void* d_out, int out_size, void* d_ws, size_t ws_size,
                              hipStream_t stream)
{
  (void)in_sizes; (void)n_in; (void)out_size; (void)ws_size;
  const float* x   = (const float*)d_in[0];
  const float* qw  = (const float*)d_in[1];
  const float* kw  = (const float*)d_in[2];
  const float* vw  = (const float*)d_in[3];
  const float* vb  = (const float*)d_in[4];
  const float* gam = (const float*)d_in[5];
  const float* bnw = (const float*)d_in[6];
  const float* bnb = (const float*)d_in[7];

  char* ws = (char*)d_ws;
  f16*   qa  = (f16*)(ws);
  f16*   ka2 = (f16*)(ws + (2u << 20));
  f16*   va3 = (f16*)(ws + (4u << 20));
  float* y0  = (float*)(ws + (6u << 20));
  float* gs1 = (float*)(ws + (10u << 20));          // 64 floats
  float* gs2 = (float*)(ws + (10u << 20) + 256);    // 64 floats (contiguous)

  pam_pre  <<<1024, 256, 0, stream>>>(x, qw, kw, vw, vb, qa, ka2, va3, gs1);
  pam_attn <<<512, 512, 0, stream>>>(qa, ka2, va3, gam, y0, gs1, gs2);
  pam_apply<<<1024, 256, 0, stream>>>(y0, x, gs1, gs2, bnw, bnb, (float*)d_out);
}